// Round 8
// baseline (709.440 us; speedup 1.0000x reference)
//
#include <hip/hip_runtime.h>
#include <stdint.h>

// Problem constants: x [B=2, S=4096, K=4096] -> M = 8192; weight [N=4096, K=4096]
#define M_DIM 8192
#define N_DIM 4096
#define K_DIM 4096

using int4v = __attribute__((ext_vector_type(4))) int;

// ---------------------------------------------------------------------------
// Pack kernel: int32 (widened int8 in [-127,127]) -> int8 bytes.
// One int4 (16 B) read per thread -> 4 B write, fully coalesced.
// ---------------------------------------------------------------------------
__global__ __launch_bounds__(256) void pack_kernel(const int4* __restrict__ sx,
                                                   const int4* __restrict__ sw,
                                                   unsigned int* __restrict__ dst,
                                                   int nx, int ntot) {
    int idx = blockIdx.x * blockDim.x + threadIdx.x;
    if (idx >= ntot) return;
    int4 v = (idx < nx) ? sx[idx] : sw[idx - nx];
    dst[idx] = (v.x & 0xff) | ((v.y & 0xff) << 8) | ((v.z & 0xff) << 16) |
               ((v.w & 0xff) << 24);
}

// ---------------------------------------------------------------------------
// i8 GEMM, ZERO-LDS design (r8).
//
// Rationale (r2-r7 counters): every LDS-staged variant lands at 172-181 us
// because (a) the LDS pipe carries 48 KB/block-iter (576 cyc @ 85 B/cyc) --
// the most-loaded pipe -- and (b) __syncthreads always drains
// vmcnt(0)+lgkmcnt(0) (m97 asm), chaining staging latency to the barrier.
//
// Key observation: with K-major A AND B, the mfma_i32_16x16x64_i8 operand
// layout (lane fr=lane&15, gw=lane>>4 holds T[row+fr][k0+gw*16..+16]) is a
// contiguous aligned 16-B global load. One wave-instr = 16 rows x 4
// col-groups = 16 fully-consumed 64-B lines. So fragments load directly
// global->VGPR: no LDS, no barriers, waves free-run, MFMA/VMEM overlap
// naturally across 12 waves/CU. Reuse lives in L1/L2 (per K-step: B-slab
// 256 KB + x-slab 512 KB, L2-resident; wave-pairs share A lines via L1).
//
// 128x128 block tile, 4 waves in 2x2, wave tile 64x64 = 4x4 of 16x16x64.
// Frag regs ping-pong (load k+64 while computing k): 64 VGPR + 64 AGPR acc.
//
// C[m,n] = sum_k x[m,k] * w[n,k].
// C/D layout: col = lane&15, row = (lane>>4)*4 + reg.
// ---------------------------------------------------------------------------
__global__ __launch_bounds__(256, 3) void gemm_i8_kernel(
    const char* __restrict__ Aq,   // [M, K] int8
    const char* __restrict__ Bq,   // [N, K] int8
    const int* __restrict__ bias,  // [N] int32 (widened int8)
    const float* __restrict__ a_ptr,
    const float* __restrict__ b_ptr,
    int32_t* __restrict__ out)     // [M, N] int32 holding int8 values
{
    const int tid  = threadIdx.x;
    const int lane = tid & 63;
    const int wave = tid >> 6;
    const int wr   = wave >> 1;   // wave row (0..1) -> 64-row slab
    const int wc   = wave & 1;    // wave col (0..1) -> 64-col slab
    const int m0   = blockIdx.y * 128;
    const int n0   = blockIdx.x * 128;

    const float alpha = *a_ptr;
    const float beta  = *b_ptr;

    int4v acc[4][4] = {};  // 64 AGPRs

    // Per-lane fragment base pointers. Fragment i lives at +i*16 rows.
    const int fr = lane & 15;
    const int fk = (lane >> 4) * 16;
    const char* aRow = Aq + (size_t)(m0 + wr * 64 + fr) * K_DIM + fk;
    const char* bRow = Bq + (size_t)(n0 + wc * 64 + fr) * K_DIM + fk;
    const size_t rstep = (size_t)16 * K_DIM;  // 16-row stride

    int4v af0[4], bf0[4], af1[4], bf1[4];

    // Prologue: fragments for k=0.
#pragma unroll
    for (int i = 0; i < 4; ++i) {
        af0[i] = *(const int4v*)(aRow + (size_t)i * rstep);
        bf0[i] = *(const int4v*)(bRow + (size_t)i * rstep);
    }

    for (int k0 = 0; k0 < K_DIM; k0 += 128) {
        // Prefetch k0+64 while computing k0.
#pragma unroll
        for (int i = 0; i < 4; ++i) {
            af1[i] = *(const int4v*)(aRow + (size_t)i * rstep + k0 + 64);
            bf1[i] = *(const int4v*)(bRow + (size_t)i * rstep + k0 + 64);
        }
#pragma unroll
        for (int i = 0; i < 4; ++i)
#pragma unroll
            for (int j = 0; j < 4; ++j)
                acc[i][j] = __builtin_amdgcn_mfma_i32_16x16x64_i8(
                    af0[i], bf0[j], acc[i][j], 0, 0, 0);

        // Prefetch k0+128 while computing k0+64.
        if (k0 + 128 < K_DIM) {
#pragma unroll
            for (int i = 0; i < 4; ++i) {
                af0[i] = *(const int4v*)(aRow + (size_t)i * rstep + k0 + 128);
                bf0[i] = *(const int4v*)(bRow + (size_t)i * rstep + k0 + 128);
            }
        }
#pragma unroll
        for (int i = 0; i < 4; ++i)
#pragma unroll
            for (int j = 0; j < 4; ++j)
                acc[i][j] = __builtin_amdgcn_mfma_i32_16x16x64_i8(
                    af1[i], bf1[j], acc[i][j], 0, 0, 0);
    }

    // Epilogue: C/D layout col = lane&15, row = (lane>>4)*4 + reg.
    const int orow = (lane >> 4) * 4;
    const int ocol = lane & 15;
#pragma unroll
    for (int j = 0; j < 4; ++j) {
        const int gn = n0 + wc * 64 + j * 16 + ocol;
        const float bb = beta * (float)bias[gn];
#pragma unroll
        for (int i = 0; i < 4; ++i) {
            const int gm = m0 + wr * 64 + i * 16 + orow;
#pragma unroll
            for (int r = 0; r < 4; ++r) {
                float v = alpha * (float)acc[i][j][r] + bb;
                v = rintf(v);                       // round half-to-even (numpy)
                v = fminf(fmaxf(v, -128.0f), 127.0f);
                out[(size_t)(gm + r) * N_DIM + gn] = (int32_t)v;
            }
        }
    }
}

// ---------------------------------------------------------------------------
extern "C" void kernel_launch(void* const* d_in, const int* in_sizes, int n_in,
                              void* d_out, int out_size, void* d_ws, size_t ws_size,
                              hipStream_t stream) {
    const int*   x    = (const int*)d_in[0];    // [M, K] widened int8
    const int*   w    = (const int*)d_in[1];    // [N, K] widened int8
    const int*   bias = (const int*)d_in[2];    // [N]
    const float* a    = (const float*)d_in[3];  // alpha scalar
    const float* b    = (const float*)d_in[4];  // beta scalar
    int32_t*     out  = (int32_t*)d_out;        // [M, N]

    char* xq = (char*)d_ws;                     // 32 MiB packed x
    const int nx   = (M_DIM * K_DIM) / 4;       // int4-groups in x
    const int nw   = (N_DIM * K_DIM) / 4;
    const int ntot = nx + nw;
    pack_kernel<<<(ntot + 255) / 256, 256, 0, stream>>>(
        (const int4*)x, (const int4*)w, (unsigned int*)xq, nx, ntot);

    char* wq = xq + (size_t)M_DIM * K_DIM;      // 16 MiB packed weight

    dim3 grid(N_DIM / 128, M_DIM / 128);        // 32 x 64 = 2048 blocks
    gemm_i8_kernel<<<grid, 256, 0, stream>>>(xq, wq, bias, a, b, out);
}

// Round 9
// 472.062 us; speedup vs baseline: 1.5029x; 1.5029x over previous
//
#include <hip/hip_runtime.h>
#include <stdint.h>

// Problem constants: x [B=2, S=4096, K=4096] -> M = 8192; weight [N=4096, K=4096]
#define M_DIM 8192
#define N_DIM 4096
#define K_DIM 4096

using int4v  = __attribute__((ext_vector_type(4))) int;
using int16v = __attribute__((ext_vector_type(16))) int;

// ---------------------------------------------------------------------------
// Pack kernel: int32 (widened int8 in [-127,127]) -> int8 bytes.
// One int4 (16 B) read per thread -> 4 B write, fully coalesced.
// ---------------------------------------------------------------------------
__global__ __launch_bounds__(256) void pack_kernel(const int4* __restrict__ sx,
                                                   const int4* __restrict__ sw,
                                                   unsigned int* __restrict__ dst,
                                                   int nx, int ntot) {
    int idx = blockIdx.x * blockDim.x + threadIdx.x;
    if (idx >= ntot) return;
    int4 v = (idx < nx) ? sx[idx] : sw[idx - nx];
    dst[idx] = (v.x & 0xff) | ((v.y & 0xff) << 8) | ((v.z & 0xff) << 16) |
               ((v.w & 0xff) << 24);
}

// ---------------------------------------------------------------------------
// Async global -> LDS copy, 16 B per lane (global_load_lds_dwordx4).
// ---------------------------------------------------------------------------
__device__ __forceinline__ void async_copy16(const char* g, char* l) {
    __builtin_amdgcn_global_load_lds(
        (const __attribute__((address_space(1))) char*)g,
        (__attribute__((address_space(3))) char*)l, 16, 0, 0);
}

// ---------------------------------------------------------------------------
// i8 GEMM, 256x256 block tile (r9): L2-traffic-limited plateau diagnosis --
// all 128x128 variants stage 16KB/2^20 MACs = 2.0 GB/dispatch = 11.7 TB/s
// sustained from L2 at 172 us = the measured L2 ceiling (56 B/cyc/CU).
// 256x256 halves staged bytes per MAC (8KB/2^20) -> ~1.0 GB/dispatch.
//
// 256 threads = 4 waves in 2x2; wave tile 128x128 = 4x4 of 32x32x32 i8
// MFMAs (A/B/C layouts verified in r3). acc = 256 AGPRs -> 1 wave/SIMD.
// LDS: double-buffered A 256x64 + B 256x64 = 64 KiB.
// Single barrier per K-iter (r4 structure): prefetch tile k+1 via
// global_load_lds right after the barrier; by the next barrier those loads
// are a full ~1170-cyc MFMA phase old -> the vmcnt(0) drain is cheap.
//
// Bank swizzle (r5, verified 0 conflicts): LDS 16-B chunk (row, gs) holds
// global col-group gs ^ ((row>>1)&3). Works for any fragment pattern whose
// consecutive-8-lane groups cover 8 consecutive rows (true for 32-row frags).
//
// C[m,n] = sum_k x[m,k] * w[n,k]  (both operands K-major).
// 32x32 A/B frag: row=lane&31, k-group=lane>>5 (16 B).
// 32x32 C/D frag: col=lane&31, row=(reg&3)+8*(reg>>2)+4*(lane>>5).
// ---------------------------------------------------------------------------
__global__ __launch_bounds__(256, 1) void gemm_i8_kernel(
    const char* __restrict__ Aq,   // [M, K] int8
    const char* __restrict__ Bq,   // [N, K] int8
    const int* __restrict__ bias,  // [N] int32 (widened int8)
    const float* __restrict__ a_ptr,
    const float* __restrict__ b_ptr,
    int32_t* __restrict__ out)     // [M, N] int32 holding int8 values
{
    __shared__ char As[2][256 * 64];   // 2 x 16 KiB
    __shared__ char Bs[2][256 * 64];   // 2 x 16 KiB

    const int tid  = threadIdx.x;
    const int lane = tid & 63;
    const int wave = tid >> 6;
    const int wr   = wave >> 1;   // wave row (0..1) -> 128 M-rows
    const int wc   = wave & 1;    // wave col (0..1) -> 128 N-cols
    const int m0   = blockIdx.y * 256;
    const int n0   = blockIdx.x * 256;

    const float alpha = *a_ptr;
    const float beta  = *b_ptr;

    int16v acc[4][4] = {};  // 256 accumulator regs (AGPR)

    // Staging: thread t owns 16-B chunks {t, t+256, t+512, t+768} of each
    // tile -> rows srow + 64q (swizzle key invariant: 64 = 0 mod 8).
    const int srow = tid >> 2;                        // 0..63
    const int scol = ((tid & 3) ^ ((srow >> 1) & 3)) * 16;

    const char* aG = Aq + (size_t)(m0 + srow) * K_DIM + scol;
    const char* bG = Bq + (size_t)(n0 + srow) * K_DIM + scol;
    const size_t q64 = (size_t)64 * K_DIM;
    const int l16 = tid * 16;

    // Fragment read coords: lane fr=lane&31, gw=lane>>5; phase kk uses
    // global col-groups {2kk, 2kk+1}; swizzle key = (fr>>1)&3 (wr*128,
    // i*32 are 0 mod 8).
    const int fr   = lane & 31;
    const int gw   = lane >> 5;
    const int fkey = (fr >> 1) & 3;

    // Prologue: stage tile 0 into buffer 0.
#pragma unroll
    for (int q = 0; q < 4; ++q) {
        async_copy16(aG + q * q64, &As[0][l16 + 4096 * q]);
        async_copy16(bG + q * q64, &Bs[0][l16 + 4096 * q]);
    }
    __syncthreads();

    for (int k0 = 0; k0 < K_DIM; k0 += 64) {
        const int cur = (k0 >> 6) & 1;
        const int nxt = cur ^ 1;

        // Prefetch tile k+1 into the buffer freed by the last barrier.
        if (k0 + 64 < K_DIM) {
#pragma unroll
            for (int q = 0; q < 4; ++q) {
                async_copy16(aG + q * q64 + k0 + 64, &As[nxt][l16 + 4096 * q]);
                async_copy16(bG + q * q64 + k0 + 64, &Bs[nxt][l16 + 4096 * q]);
            }
        }

        int4v af[2][4], bf[2][4];
#pragma unroll
        for (int kk = 0; kk < 2; ++kk)
#pragma unroll
            for (int i = 0; i < 4; ++i) {
                const int co = (((2 * kk + gw) ^ fkey) * 16);
                af[kk][i] = *(const int4v*)
                    &As[cur][(wr * 128 + i * 32 + fr) * 64 + co];
                bf[kk][i] = *(const int4v*)
                    &Bs[cur][(wc * 128 + i * 32 + fr) * 64 + co];
            }

#pragma unroll
        for (int kk = 0; kk < 2; ++kk)
#pragma unroll
            for (int i = 0; i < 4; ++i)
#pragma unroll
                for (int j = 0; j < 4; ++j)
                    acc[i][j] = __builtin_amdgcn_mfma_i32_32x32x32_i8(
                        af[kk][i], bf[kk][j], acc[i][j], 0, 0, 0);

        // Single barrier: next iter's reads of buf(nxt) see these prefetch
        // writes (vmcnt drain cheap: loads are ~1 full MFMA phase old), and
        // this iter's reads of buf(cur) finish before iter k+2 overwrites.
        __syncthreads();
    }

    // Epilogue: C/D col = lane&31, row = (reg&3) + 8*(reg>>2) + 4*(lane>>5).
    const int ocol  = lane & 31;
    const int rbase = (lane >> 5) * 4;
#pragma unroll
    for (int j = 0; j < 4; ++j) {
        const int gn = n0 + wc * 128 + j * 32 + ocol;
        const float bb = beta * (float)bias[gn];
#pragma unroll
        for (int i = 0; i < 4; ++i) {
            const int gm = m0 + wr * 128 + i * 32;
#pragma unroll
            for (int r = 0; r < 16; ++r) {
                const int row = (r & 3) + 8 * (r >> 2) + rbase;
                float v = alpha * (float)acc[i][j][r] + bb;
                v = rintf(v);                       // round half-to-even (numpy)
                v = fminf(fmaxf(v, -128.0f), 127.0f);
                out[(size_t)(gm + row) * N_DIM + gn] = (int32_t)v;
            }
        }
    }
}

// ---------------------------------------------------------------------------
extern "C" void kernel_launch(void* const* d_in, const int* in_sizes, int n_in,
                              void* d_out, int out_size, void* d_ws, size_t ws_size,
                              hipStream_t stream) {
    const int*   x    = (const int*)d_in[0];    // [M, K] widened int8
    const int*   w    = (const int*)d_in[1];    // [N, K] widened int8
    const int*   bias = (const int*)d_in[2];    // [N]
    const float* a    = (const float*)d_in[3];  // alpha scalar
    const float* b    = (const float*)d_in[4];  // beta scalar
    int32_t*     out  = (int32_t*)d_out;        // [M, N]

    char* xq = (char*)d_ws;                     // 32 MiB packed x
    const int nx   = (M_DIM * K_DIM) / 4;       // int4-groups in x
    const int nw   = (N_DIM * K_DIM) / 4;
    const int ntot = nx + nw;
    pack_kernel<<<(ntot + 255) / 256, 256, 0, stream>>>(
        (const int4*)x, (const int4*)w, (unsigned int*)xq, nx, ntot);

    char* wq = xq + (size_t)M_DIM * K_DIM;      // 16 MiB packed weight

    dim3 grid(N_DIM / 256, M_DIM / 256);        // 16 x 32 = 512 blocks
    gemm_i8_kernel<<<grid, 256, 0, stream>>>(xq, wq, bias, a, b, out);
}

// Round 10
// 415.063 us; speedup vs baseline: 1.7092x; 1.1373x over previous
//
#include <hip/hip_runtime.h>
#include <stdint.h>

// Problem constants: x [B=2, S=4096, K=4096] -> M = 8192; weight [N=4096, K=4096]
#define M_DIM 8192
#define N_DIM 4096
#define K_DIM 4096

using int4v = __attribute__((ext_vector_type(4))) int;

// ---------------------------------------------------------------------------
// Pack kernel: int32 (widened int8 in [-127,127]) -> int8 bytes.
// One int4 (16 B) read per thread -> 4 B write, fully coalesced.
// ---------------------------------------------------------------------------
__global__ __launch_bounds__(256) void pack_kernel(const int4* __restrict__ sx,
                                                   const int4* __restrict__ sw,
                                                   unsigned int* __restrict__ dst,
                                                   int nx, int ntot) {
    int idx = blockIdx.x * blockDim.x + threadIdx.x;
    if (idx >= ntot) return;
    int4 v = (idx < nx) ? sx[idx] : sw[idx - nx];
    dst[idx] = (v.x & 0xff) | ((v.y & 0xff) << 8) | ((v.z & 0xff) << 16) |
               ((v.w & 0xff) << 24);
}

// ---------------------------------------------------------------------------
// i8 GEMM, r10 = r7 (best: 172 us) + __launch_bounds__(256,4).
//
// Corrected model (r9 post-mortem): r7 is LATENCY-bound, not pipe-bound --
// per-CU utilization at 3 blocks/CU: LDS 54%, MFMA 40%, VMEM 36%, VALU 16%,
// issue ~25%. No pipe saturated; all 12-waves/CU variants tie (172-181 us),
// and both lower-occupancy variants (r6: 8 w/CU -> 180, r9: 4 w/CU -> 273)
// regress in proportion. Resources allow 4 blocks/CU (LDS 4x32=128<=160 KiB;
// regs 64 VGPR + 64 AGPR = 128 = 512/4): raise the floor by declaring
// __launch_bounds__(256,4) so the allocator fits 4 waves/SIMD.
//
// Structure (r7): 128x128 block tile, 4 waves 2x2, wave 64x64 = 4x4 of
// mfma_i32_16x16x64_i8. Register-staged double-buffered LDS (buffer_load ->
// VGPR -> ds_write), one barrier per K-iter; 2-deep pipeline: load k+2 /
// write k+1 / compute k. Bank swizzle (r5, measured 0 conflicts): LDS 16-B
// chunk (row, gs) holds global col-group gs ^ ((row>>1)&3).
//
// C[m,n] = sum_k x[m,k] * w[n,k]  (both operands K-major).
// A/B frag: m=lane&15, k-group=lane>>4.  C/D: col=lane&15, row=(lane>>4)*4+reg.
// ---------------------------------------------------------------------------
__global__ __launch_bounds__(256, 4) void gemm_i8_kernel(
    const char* __restrict__ Aq,   // [M, K] int8
    const char* __restrict__ Bq,   // [N, K] int8
    const int* __restrict__ bias,  // [N] int32 (widened int8)
    const float* __restrict__ a_ptr,
    const float* __restrict__ b_ptr,
    int32_t* __restrict__ out)     // [M, N] int32 holding int8 values
{
    __shared__ char As[2][128 * 64];   // 2 x 8 KiB
    __shared__ char Bs[2][128 * 64];   // 2 x 8 KiB

    const int tid  = threadIdx.x;
    const int lane = tid & 63;
    const int wave = tid >> 6;
    const int wr   = wave >> 1;   // wave row (0..1) -> 64-row slab
    const int wc   = wave & 1;    // wave col (0..1) -> 64-col slab
    const int m0   = blockIdx.y * 128;
    const int n0   = blockIdx.x * 128;

    const float alpha = *a_ptr;
    const float beta  = *b_ptr;

    int4v acc[4][4] = {};  // 64 accumulator regs

    // Staging: thread t owns LDS chunk t (row = t>>2), swizzled col-group.
    const int srow = tid >> 2;                        // 0..63
    const int scol = ((tid & 3) ^ ((srow >> 1) & 3)) * 16;

    const char* aG0 = Aq + (size_t)(m0 + srow) * K_DIM + scol;
    const char* aG1 = aG0 + (size_t)64 * K_DIM;
    const char* bG0 = Bq + (size_t)(n0 + srow) * K_DIM + scol;
    const char* bG1 = bG0 + (size_t)64 * K_DIM;
    const int l0 = tid * 16;
    const int l1 = tid * 16 + 4096;

    // Fragment read coords: lane holds A[m=lane&15][k-group=lane>>4], with
    // the swizzle XOR folded into the byte offset (key = (fr>>1)&3).
    const int fr  = lane & 15;
    const int gw  = lane >> 4;
    const int fko = (gw ^ ((fr >> 1) & 3)) * 16;

    // --- Prologue: tile 0 -> regs -> LDS[0]; tile 1 -> regs. ---
    int4v ra0 = *(const int4v*)aG0;
    int4v ra1 = *(const int4v*)aG1;
    int4v rb0 = *(const int4v*)bG0;
    int4v rb1 = *(const int4v*)bG1;
    *(int4v*)&As[0][l0] = ra0;
    *(int4v*)&As[0][l1] = ra1;
    *(int4v*)&Bs[0][l0] = rb0;
    *(int4v*)&Bs[0][l1] = rb1;
    ra0 = *(const int4v*)(aG0 + 64);
    ra1 = *(const int4v*)(aG1 + 64);
    rb0 = *(const int4v*)(bG0 + 64);
    rb1 = *(const int4v*)(bG1 + 64);
    __syncthreads();  // tile-0 ds_writes visible

#pragma unroll 2
    for (int k0 = 0; k0 < K_DIM; k0 += 64) {
        const int cur = (k0 >> 6) & 1;
        const int nxt = cur ^ 1;

        // Stage tile k+1 (regs, loaded last iter -> vmcnt wait ~1 iter old)
        // into the buffer the previous iter finished reading.
        if (k0 + 64 < K_DIM) {
            *(int4v*)&As[nxt][l0] = ra0;
            *(int4v*)&As[nxt][l1] = ra1;
            *(int4v*)&Bs[nxt][l0] = rb0;
            *(int4v*)&Bs[nxt][l1] = rb1;
        }
        // Issue global loads for tile k+2 (consumed next iter).
        if (k0 + 128 < K_DIM) {
            ra0 = *(const int4v*)(aG0 + k0 + 128);
            ra1 = *(const int4v*)(aG1 + k0 + 128);
            rb0 = *(const int4v*)(bG0 + k0 + 128);
            rb1 = *(const int4v*)(bG1 + k0 + 128);
        }

        int4v af[4], bf[4];
#pragma unroll
        for (int i = 0; i < 4; ++i)
            af[i] = *(const int4v*)&As[cur][(wr * 64 + i * 16 + fr) * 64 + fko];
#pragma unroll
        for (int j = 0; j < 4; ++j)
            bf[j] = *(const int4v*)&Bs[cur][(wc * 64 + j * 16 + fr) * 64 + fko];

#pragma unroll
        for (int i = 0; i < 4; ++i)
#pragma unroll
            for (int j = 0; j < 4; ++j)
                acc[i][j] = __builtin_amdgcn_mfma_i32_16x16x64_i8(
                    af[i], bf[j], acc[i][j], 0, 0, 0);

        __syncthreads();
    }

    // Epilogue: C/D layout col = lane&15, row = (lane>>4)*4 + reg.
    const int orow = (lane >> 4) * 4;
    const int ocol = lane & 15;
#pragma unroll
    for (int j = 0; j < 4; ++j) {
        const int gn = n0 + wc * 64 + j * 16 + ocol;
        const float bb = beta * (float)bias[gn];
#pragma unroll
        for (int i = 0; i < 4; ++i) {
            const int gm = m0 + wr * 64 + i * 16 + orow;
#pragma unroll
            for (int r = 0; r < 4; ++r) {
                float v = alpha * (float)acc[i][j][r] + bb;
                v = rintf(v);                       // round half-to-even (numpy)
                v = fminf(fmaxf(v, -128.0f), 127.0f);
                out[(size_t)(gm + r) * N_DIM + gn] = (int32_t)v;
            }
        }
    }
}

// ---------------------------------------------------------------------------
extern "C" void kernel_launch(void* const* d_in, const int* in_sizes, int n_in,
                              void* d_out, int out_size, void* d_ws, size_t ws_size,
                              hipStream_t stream) {
    const int*   x    = (const int*)d_in[0];    // [M, K] widened int8
    const int*   w    = (const int*)d_in[1];    // [N, K] widened int8
    const int*   bias = (const int*)d_in[2];    // [N]
    const float* a    = (const float*)d_in[3];  // alpha scalar
    const float* b    = (const float*)d_in[4];  // beta scalar
    int32_t*     out  = (int32_t*)d_out;        // [M, N]

    char* xq = (char*)d_ws;                     // 32 MiB packed x
    const int nx   = (M_DIM * K_DIM) / 4;       // int4-groups in x
    const int nw   = (N_DIM * K_DIM) / 4;
    const int ntot = nx + nw;
    pack_kernel<<<(ntot + 255) / 256, 256, 0, stream>>>(
        (const int4*)x, (const int4*)w, (unsigned int*)xq, nx, ntot);

    char* wq = xq + (size_t)M_DIM * K_DIM;      // 16 MiB packed weight

    dim3 grid(N_DIM / 128, M_DIM / 128);        // 32 x 64 = 2048 blocks
    gemm_i8_kernel<<<grid, 256, 0, stream>>>(xq, wq, bias, a, b, out);
}